// Round 7
// baseline (555.531 us; speedup 1.0000x reference)
//
#include <hip/hip_runtime.h>
#include <math.h>

// Problem constants (fixed by setup_inputs)
#define Bb 8
#define Cc 192
#define NHEADS 8
#define HDim 24
#define Him 128
#define Wim 128
#define Ntok 16384   // H*W
#define EPSBN 1e-5f

typedef __bf16 bf16x8 __attribute__((ext_vector_type(8)));
typedef __bf16 bf16x2 __attribute__((ext_vector_type(2)));
typedef float  f32x4  __attribute__((ext_vector_type(4)));

static __device__ __forceinline__ float gelu_f(float v) {
    return 0.5f * v * (1.0f + erff(v * 0.70710678118654752f));
}
static __device__ __forceinline__ float sigmoid_f(float v) {
    return 1.0f / (1.0f + expf(-v));
}
static __device__ __forceinline__ void split8(const float* xv, bf16x8& h8, bf16x8& l8) {
#pragma unroll
    for (int j = 0; j < 8; ++j) {
        float v = xv[j];
        __bf16 h = (__bf16)v;
        h8[j] = h;
        l8[j] = (__bf16)(v - (float)h);
    }
}

// ---------------------------------------------------------------------------
// K0: one-time prep: transpose v-part of w_qkv (192x192 fp32, cols 384..575)
// into bf16 hi/lo planes in [col][k] layout. Stored in tail of d_out.
// ---------------------------------------------------------------------------
__global__ __launch_bounds__(256) void k_wprep(const float* __restrict__ w,
                                               __bf16* __restrict__ wt)
{
    int idx = blockIdx.x * 256 + threadIdx.x;   // 192*192 = 36864 total
    if (idx >= 36864) return;
    int k = idx / 192, c = idx % 192;           // coalesced read over c
    float v = w[k * 576 + 384 + c];
    __bf16 h = (__bf16)v;
    __bf16 l = (__bf16)(v - (float)h);
    wt[c * 192 + k] = h;
    wt[36864 + c * 192 + k] = l;
}

// ---------------------------------------------------------------------------
// K_xtx v4: per-batch input Gram partials via LDS-transposed staging +
// T14 register prefetch (verified round 6).
// ---------------------------------------------------------------------------
__global__ __launch_bounds__(512, 2) void k_xtx(const float* __restrict__ x,
                                                float* __restrict__ xpart)
{
    __shared__ __align__(16) __bf16 Th[192 * 40];
    __shared__ __align__(16) __bf16 Tl[192 * 40];
    const int t = threadIdx.x;
    const int lane = t & 63, wave = t >> 6;   // 8 waves
    const int chunk = blockIdx.x;      // 32 chunks of 512 tokens
    const int b = blockIdx.y;
    const int n0 = chunk * 512;
    const int m16 = lane & 15, q = lane >> 4;
    const int rq = (wave & 1) * 6;     // row 16-ch-tile base (2 groups of 96)
    const int cq = (wave >> 1) * 3;    // col 16-ch-tile base (4 groups of 48)

    f32x4 acc[6][3];
#pragma unroll
    for (int i = 0; i < 6; ++i)
#pragma unroll
        for (int j = 0; j < 3; ++j)
#pragma unroll
            for (int r = 0; r < 4; ++r) acc[i][j][r] = 0.f;

    // staging units: u = (ch4-group, token-pair); 48*16 = 768 units.
    const int ch4_0 = (t % 48) * 4, tk_0 = (t / 48) * 2;
    const int u1 = 512 + t;
    const int ch4_1 = (u1 % 48) * 4, tk_1 = (u1 / 48) * 2;
    const bool has2 = (t < 256);
    const float* xb = x + ((size_t)b * Ntok + n0) * 192;

    float4 a0, c0, a1, c1;
    {   // preload ks = 0
        const float* p = xb + (size_t)tk_0 * 192 + ch4_0;
        a0 = *(const float4*)p;
        c0 = *(const float4*)(p + 192);
        if (has2) {
            const float* p2 = xb + (size_t)tk_1 * 192 + ch4_1;
            a1 = *(const float4*)p2;
            c1 = *(const float4*)(p2 + 192);
        }
    }

    for (int ks = 0; ks < 16; ++ks) {
        __syncthreads();
        {   // write current regs to LDS (swizzled transpose layout)
#pragma unroll
            for (int cix = 0; cix < 4; ++cix) {
                int ch = ch4_0 + cix;
                float v0 = (&a0.x)[cix], v1 = (&c0.x)[cix];
                __bf16 h0 = (__bf16)v0, h1 = (__bf16)v1;
                __bf16 l0 = (__bf16)(v0 - (float)h0);
                __bf16 l1 = (__bf16)(v1 - (float)h1);
                int o = ch * 40 + ((((tk_0 >> 3) + (ch >> 3)) & 3) << 3) + (tk_0 & 7);
                bf16x2 hp; hp[0] = h0; hp[1] = h1;
                bf16x2 lp; lp[0] = l0; lp[1] = l1;
                *(bf16x2*)&Th[o] = hp;
                *(bf16x2*)&Tl[o] = lp;
            }
            if (has2) {
#pragma unroll
                for (int cix = 0; cix < 4; ++cix) {
                    int ch = ch4_1 + cix;
                    float v0 = (&a1.x)[cix], v1 = (&c1.x)[cix];
                    __bf16 h0 = (__bf16)v0, h1 = (__bf16)v1;
                    __bf16 l0 = (__bf16)(v0 - (float)h0);
                    __bf16 l1 = (__bf16)(v1 - (float)h1);
                    int o = ch * 40 + ((((tk_1 >> 3) + (ch >> 3)) & 3) << 3) + (tk_1 & 7);
                    bf16x2 hp; hp[0] = h0; hp[1] = h1;
                    bf16x2 lp; lp[0] = l0; lp[1] = l1;
                    *(bf16x2*)&Th[o] = hp;
                    *(bf16x2*)&Tl[o] = lp;
                }
            }
        }
        if (ks < 15) {   // prefetch ks+1 into regs (flies across barriers)
            const float* p = xb + (size_t)((ks + 1) * 32 + tk_0) * 192 + ch4_0;
            a0 = *(const float4*)p;
            c0 = *(const float4*)(p + 192);
            if (has2) {
                const float* p2 = xb + (size_t)((ks + 1) * 32 + tk_1) * 192 + ch4_1;
                a1 = *(const float4*)p2;
                c1 = *(const float4*)(p2 + 192);
            }
        }
        __syncthreads();

        bf16x8 fah[6], fal[6];
#pragma unroll
        for (int ti = 0; ti < 6; ++ti) {
            int ch = (rq + ti) * 16 + m16;
            int o = ch * 40 + (((q + (ch >> 3)) & 3) << 3);
            fah[ti] = *(const bf16x8*)&Th[o];
            fal[ti] = *(const bf16x8*)&Tl[o];
        }
#pragma unroll
        for (int tj = 0; tj < 3; ++tj) {
            int ch = (cq + tj) * 16 + m16;
            int o = ch * 40 + (((q + (ch >> 3)) & 3) << 3);
            bf16x8 fbh = *(const bf16x8*)&Th[o];
            bf16x8 fbl = *(const bf16x8*)&Tl[o];
#pragma unroll
            for (int ti = 0; ti < 6; ++ti) {
                f32x4& a = acc[ti][tj];
                a = __builtin_amdgcn_mfma_f32_16x16x32_bf16(fah[ti], fbh, a, 0, 0, 0);
                a = __builtin_amdgcn_mfma_f32_16x16x32_bf16(fah[ti], fbl, a, 0, 0, 0);
                a = __builtin_amdgcn_mfma_f32_16x16x32_bf16(fal[ti], fbh, a, 0, 0, 0);
            }
        }
    }
    float* op = xpart + ((size_t)b * 32 + chunk) * 36864;
#pragma unroll
    for (int ti = 0; ti < 6; ++ti)
#pragma unroll
        for (int tj = 0; tj < 3; ++tj) {
            const int row0 = (rq + ti) * 16 + q * 4;
            const int col = (cq + tj) * 16 + m16;
#pragma unroll
            for (int j = 0; j < 4; ++j)
                op[(size_t)(row0 + j) * 192 + col] = acc[ti][tj][j];
        }
}

// ---------------------------------------------------------------------------
// K_xred: reduce 32 chunk-partials -> XtX[b] (192x192 per batch).
// ---------------------------------------------------------------------------
__global__ __launch_bounds__(256) void k_xred(const float* __restrict__ xpart,
                                              float* __restrict__ XtX)
{
    const int b = blockIdx.y;
    const int e = blockIdx.x * 256 + threadIdx.x;   // 36864 = 144*256
    const float* p = xpart + (size_t)b * 32 * 36864 + e;
    float s = 0.f;
#pragma unroll
    for (int c = 0; c < 32; ++c) s += p[(size_t)c * 36864];
    XtX[(size_t)b * 36864 + e] = s;
}

// ---------------------------------------------------------------------------
// K_gram2: gram[b,h] = Wq_h^T XtX_b Wk_h; ssq_q[c] = Wq_c^T XtX Wq_c;
// ssq_k likewise. All fp32. Grid (B, HEADS).
// ---------------------------------------------------------------------------
__global__ __launch_bounds__(256) void k_gram2(const float* __restrict__ XtX,
                                               const float* __restrict__ w_qkv,
                                               float* __restrict__ gram,
                                               float* __restrict__ ssq_q,
                                               float* __restrict__ ssq_k)
{
    __shared__ float wq[192][24];
    __shared__ float wk[192][24];
    __shared__ float U[192][24];
    __shared__ float V[192][24];
    const int b = blockIdx.x, h = blockIdx.y, t = threadIdx.x;
    for (int e = t; e < 4608; e += 256) {
        int k = e / 24, c = e % 24;
        wq[k][c] = w_qkv[k * 576 + h * 24 + c];
        wk[k][c] = w_qkv[k * 576 + 192 + h * 24 + c];
    }
    __syncthreads();
    if (t < 192) {
        const float* xr = XtX + (size_t)b * 36864 + (size_t)t * 192;
        float u[24], v[24];
#pragma unroll
        for (int c = 0; c < 24; ++c) { u[c] = 0.f; v[c] = 0.f; }
        for (int k4 = 0; k4 < 48; ++k4) {
            float4 x4 = *(const float4*)(xr + k4 * 4);
#pragma unroll
            for (int kk = 0; kk < 4; ++kk) {
                float xv = (&x4.x)[kk];
                int k = k4 * 4 + kk;
#pragma unroll
                for (int c = 0; c < 24; ++c) {
                    u[c] = fmaf(xv, wq[k][c], u[c]);
                    v[c] = fmaf(xv, wk[k][c], v[c]);
                }
            }
        }
#pragma unroll
        for (int c = 0; c < 24; ++c) { U[t][c] = u[c]; V[t][c] = v[c]; }
    }
    __syncthreads();
    for (int o = t; o < 576; o += 256) {
        int c = o / 24, d = o % 24;
        float g = 0.f;
        for (int r = 0; r < 192; ++r) g = fmaf(wq[r][c], V[r][d], g);
        gram[(size_t)(b * NHEADS + h) * 576 + o] = g;
    }
    if (t < 24) {
        float s = 0.f;
        for (int r = 0; r < 192; ++r) s = fmaf(wq[r][t], U[r][t], s);
        ssq_q[b * Cc + h * HDim + t] = s;
    } else if (t < 48) {
        int c = t - 24;
        float s = 0.f;
        for (int r = 0; r < 192; ++r) s = fmaf(wk[r][c], V[r][c], s);
        ssq_k[b * Cc + h * HDim + c] = s;
    }
}

// ---------------------------------------------------------------------------
// K1 (v-only) v3: 64-token blocks to cut unified regs 240 -> ~155 and allow
// 3 blocks/CU (was 2 waves/SIMD hard cap). Wave tile 32 tok x 96 col,
// acc[2][6] = 48 AGPR. B staged per kc as before; + T14 A prefetch.
// ---------------------------------------------------------------------------
__global__ __launch_bounds__(256, 3) void k_qkv_mfma(const float* __restrict__ x,
                                                     const __bf16* __restrict__ wt,
                                                     float* __restrict__ vout,
                                                     float* __restrict__ vsum)
{
    __shared__ __align__(16) __bf16 Ah[64 * 40];
    __shared__ __align__(16) __bf16 Al[64 * 40];
    __shared__ __align__(16) __bf16 Bh[192 * 40];
    __shared__ __align__(16) __bf16 Bl[192 * 40];

    const int t = threadIdx.x;
    const int lane = t & 63, wave = t >> 6;
    const int n0 = blockIdx.x * 64;
    const int b = blockIdx.y;
    const int row_base = (wave & 1) * 32;
    const int col_base = (wave >> 1) * 96;
    const int m16 = lane & 15, q = lane >> 4;

    f32x4 acc[2][6];
#pragma unroll
    for (int rt = 0; rt < 2; ++rt)
#pragma unroll
        for (int ct = 0; ct < 6; ++ct)
#pragma unroll
            for (int j = 0; j < 4; ++j) acc[rt][ct][j] = 0.f;

    const int ar = t >> 2, ac8 = (t & 3) * 8;   // token-in-block, 8-ch group
    const float* xrow = x + ((size_t)b * Ntok + n0 + ar) * Cc + ac8;

    float4 pa0, pa1;
    pa0 = *(const float4*)xrow;
    pa1 = *(const float4*)(xrow + 4);

    for (int kc = 0; kc < 6; ++kc) {
        {   // stage A from prefetched regs
            float xv[8];
            xv[0] = pa0.x; xv[1] = pa0.y; xv[2] = pa0.z; xv[3] = pa0.w;
            xv[4] = pa1.x; xv[5] = pa1.y; xv[6] = pa1.z; xv[7] = pa1.w;
            bf16x8 vh0, vl0;
            split8(xv, vh0, vl0);
            const int o = ar * 40 + ac8;
            *(bf16x8*)&Ah[o] = vh0;
            *(bf16x8*)&Al[o] = vl0;
        }
#pragma unroll
        for (int i = 0; i < 3; ++i) {
            int f = i * 256 + t;
            int n = f >> 2, k8 = (f & 3) << 3;
            const __bf16* src = wt + (size_t)n * 192 + kc * 32 + k8;
            bf16x8 vh = *(const bf16x8*)src;
            bf16x8 vl = *(const bf16x8*)(src + 36864);
            *(bf16x8*)&Bh[n * 40 + k8] = vh;
            *(bf16x8*)&Bl[n * 40 + k8] = vl;
        }
        if (kc < 5) {   // prefetch next kc's A (flies across barriers)
            pa0 = *(const float4*)(xrow + (kc + 1) * 32);
            pa1 = *(const float4*)(xrow + (kc + 1) * 32 + 4);
        }
        __syncthreads();

        bf16x8 fah[2], fal[2], fbh[6], fbl[6];
#pragma unroll
        for (int rt = 0; rt < 2; ++rt) {
            int o = (row_base + rt * 16 + m16) * 40 + q * 8;
            fah[rt] = *(const bf16x8*)&Ah[o];
            fal[rt] = *(const bf16x8*)&Al[o];
        }
#pragma unroll
        for (int ct = 0; ct < 6; ++ct) {
            int o = (col_base + ct * 16 + m16) * 40 + q * 8;
            fbh[ct] = *(const bf16x8*)&Bh[o];
            fbl[ct] = *(const bf16x8*)&Bl[o];
        }
#pragma unroll
        for (int rt = 0; rt < 2; ++rt)
#pragma unroll
            for (int ct = 0; ct < 6; ++ct) {
                acc[rt][ct] = __builtin_amdgcn_mfma_f32_16x16x32_bf16(
                    fah[rt], fbh[ct], acc[rt][ct], 0, 0, 0);
                acc[rt][ct] = __builtin_amdgcn_mfma_f32_16x16x32_bf16(
                    fah[rt], fbl[ct], acc[rt][ct], 0, 0, 0);
                acc[rt][ct] = __builtin_amdgcn_mfma_f32_16x16x32_bf16(
                    fal[rt], fbh[ct], acc[rt][ct], 0, 0, 0);
            }
        __syncthreads();
    }

    const size_t obase = (size_t)b * Cc * (size_t)Ntok;
#pragma unroll
    for (int rt = 0; rt < 2; ++rt)
#pragma unroll
        for (int ct = 0; ct < 6; ++ct) {
            int token = n0 + row_base + rt * 16 + q * 4;
            int col = col_base + ct * 16 + m16;
            float4 o = make_float4(acc[rt][ct][0], acc[rt][ct][1],
                                   acc[rt][ct][2], acc[rt][ct][3]);
            *(float4*)(vout + obase + (size_t)col * Ntok + token) = o;
        }

#pragma unroll
    for (int ct = 0; ct < 6; ++ct) {
        float s = 0.f;
#pragma unroll
        for (int rt = 0; rt < 2; ++rt)
            s += acc[rt][ct][0] + acc[rt][ct][1] + acc[rt][ct][2] + acc[rt][ct][3];
        s += __shfl_xor(s, 16, 64);
        s += __shfl_xor(s, 32, 64);
        if (q == 0)
            atomicAdd(vsum + b * Cc + col_base + ct * 16 + m16, s);
    }
}

// K4: normalize gram -> softmax attn; pooled = attn @ vmean; channel-gate MLP.
__global__ __launch_bounds__(256) void k_attn(const float* __restrict__ gram,
                                              const float* __restrict__ ssq_q,
                                              const float* __restrict__ ssq_k,
                                              const float* __restrict__ temperature,
                                              const float* __restrict__ vmean,
                                              const float* __restrict__ ci_w1,
                                              const float* __restrict__ ci_b1,
                                              const float* __restrict__ bn2_g,
                                              const float* __restrict__ bn2_b,
                                              const float* __restrict__ bn2_m,
                                              const float* __restrict__ bn2_v,
                                              const float* __restrict__ ci_w2,
                                              const float* __restrict__ ci_b2,
                                              float* __restrict__ attn,
                                              float* __restrict__ sig_ch)
{
    __shared__ float pooled[192];
    __shared__ float cmv[24];
    const int b = blockIdx.x, t = threadIdx.x;
    if (t < 192) {
        int h = t / 24, c = t % 24;
        const float* gp = gram + (size_t)(b * NHEADS + h) * 576 + c * 24;
        float qn = fmaxf(sqrtf(ssq_q[b * Cc + h * HDim + c]), 1e-12f);
        float temp = temperature[h];
        float logit[24];
        float m = -1e30f;
#pragma unroll
        for (int d = 0; d < 24; ++d) {
            float kn = fmaxf(sqrtf(ssq_k[b * Cc + h * HDim + d]), 1e-12f);
            float l = gp[d] / (qn * kn) * temp;
            logit[d] = l; m = fmaxf(m, l);
        }
        float s = 0.f;
#pragma unroll
        for (int d = 0; d < 24; ++d) { float e = expf(logit[d] - m); logit[d] = e; s += e; }
        float inv = 1.f / s;
        float pool = 0.f;
        float* ap = attn + (size_t)(b * NHEADS + h) * 576 + c * 24;
#pragma unroll
        for (int d = 0; d < 24; ++d) {
            float a = logit[d] * inv;
            ap[d] = a;
            pool = fmaf(a, vmean[b * Cc + h * HDim + d], pool);
        }
        pooled[h * 24 + c] = pool * (1.0f / (float)Ntok);
    }
    __syncthreads();
    if (t < 24) {
        float z = ci_b1[t];
        for (int c = 0; c < 192; ++c) z = fmaf(ci_w1[t * 192 + c], pooled[c], z);
        float sc = bn2_g[t] / sqrtf(bn2_v[t] + EPSBN);
        z = z * sc + (bn2_b[t] - bn2_m[t] * sc);
        cmv[t] = gelu_f(z);
    }
    __syncthreads();
    if (t < 192) {
        float z = ci_b2[t];
#pragma unroll
        for (int o = 0; o < 24; ++o) z = fmaf(ci_w2[t * 24 + o], cmv[o], z);
        sig_ch[b * Cc + t] = sigmoid_f(z);
    }
}

// ---------------------------------------------------------------------------
// K4b: fold attention + channel gate into projection.
// ---------------------------------------------------------------------------
__global__ __launch_bounds__(192) void k_pprep(const float* __restrict__ attn,
                                               const float* __restrict__ sig_ch,
                                               const float* __restrict__ proj_w,
                                               __bf16* __restrict__ Pt)
{
    const int b = blockIdx.x, part = blockIdx.y, j = threadIdx.x;
    __bf16* base = Pt + (size_t)b * (2 * 73728);   // 73728 = 192*384
    if (part < 8) {
        const int h = part;
        __shared__ float at[576];
        for (int e = j; e < 576; e += 192) at[e] = attn[(size_t)(b * 8 + h) * 576 + e];
        __syncthreads();
        float pr[24];
#pragma unroll
        for (int cl = 0; cl < 24; ++cl) pr[cl] = proj_w[(h * 24 + cl) * 192 + j];
        float s[24];
#pragma unroll
        for (int d = 0; d < 24; ++d) s[d] = 0.f;
#pragma unroll
        for (int cl = 0; cl < 24; ++cl) {
            float a = pr[cl];
#pragma unroll
            for (int d = 0; d < 24; ++d) s[d] = fmaf(a, at[cl * 24 + d], s[d]);
        }
#pragma unroll
        for (int d = 0; d < 24; ++d) {
            float v = s[d];
            __bf16 hi = (__bf16)v;
            base[j * 384 + h * 24 + d] = hi;
            base[73728 + j * 384 + h * 24 + d] = (__bf16)(v - (float)hi);
        }
    } else {
        __shared__ float sch_s[192];
        sch_s[j] = sig_ch[b * Cc + j];
        __syncthreads();
        for (int ch = 0; ch < 192; ++ch) {
            float v = sch_s[ch] * proj_w[ch * 192 + j];
            __bf16 hi = (__bf16)v;
            base[j * 384 + 192 + ch] = hi;
            base[73728 + j * 384 + 192 + ch] = (__bf16)(v - (float)hi);
        }
    }
}

// ---------------------------------------------------------------------------
// K5 v3: depthwise 3x3 conv + BN1 + GELU, register-streaming (no LDS tile).
// ---------------------------------------------------------------------------
__global__ __launch_bounds__(256) void k_conv(const float* __restrict__ vbuf,
                                              const float* __restrict__ dw_w,
                                              const float* __restrict__ dw_b,
                                              const float* __restrict__ bn1_g,
                                              const float* __restrict__ bn1_b,
                                              const float* __restrict__ bn1_m,
                                              const float* __restrict__ bn1_v,
                                              float* __restrict__ convx)
{
    __shared__ float dww[72];
    __shared__ float scl[8], shf[8];
    const int t = threadIdx.x;
    const int y0 = blockIdx.x * 8;
    const int ch0 = blockIdx.y * 8;
    const int b = blockIdx.z;

    if (t < 72) {
        dww[t] = dw_w[ch0 * 9 + t];
    } else if (t < 80) {
        int c = t - 72, ch = ch0 + c;
        float sc = bn1_g[ch] / sqrtf(bn1_v[ch] + EPSBN);
        scl[c] = sc;
        shf[c] = (dw_b[ch] - bn1_m[ch]) * sc + bn1_b[ch];
    }
    __syncthreads();

    const int xq = (t & 31) * 4;        // px base 0,4,...,124
    const int r = t >> 5;               // output row within tile 0..7
    const int gy = y0 + r;

#pragma unroll
    for (int ch = 0; ch < 8; ++ch) {
        const float* base = vbuf + ((size_t)b * Cc + ch0 + ch) * Ntok;
        float v[3][6];
#pragma unroll
        for (int dy = 0; dy < 3; ++dy) {
            int iy = gy - 1 + dy;
            if (iy >= 0 && iy < Him) {
                const float* rp = base + (size_t)iy * Wim;
                float4 m = *(const float4*)(rp + xq);
                v[dy][1] = m.x; v[dy][2] = m.y; v[dy][3] = m.z; v[dy][4] = m.w;
                v[dy][0] = (xq > 0) ? rp[xq - 1] : 0.f;
                v[dy][5] = (xq < 124) ? rp[xq + 4] : 0.f;
            } else {
#pragma unroll
                for (int i2 = 0; i2 < 6; ++i2) v[dy][i2] = 0.f;
            }
        }
        const float w0 = dww[ch * 9 + 0], w1 = dww[ch * 9 + 1], w2 = dww[ch * 9 + 2];
        const float w3 = dww[ch * 9 + 3], w4 = dww[ch * 9 + 4], w5 = dww[ch * 9 + 5];
        const float w6 = dww[ch * 9 + 6], w7 = dww[ch * 9 + 7], w8 = dww[ch * 9 + 8];
        const float sc = scl[ch], sh = shf[ch];
        float4 o;
#pragma unroll
        for (int p = 0; p < 4; ++p) {
            float s = v[0][p] * w0 + v[0][p + 1] * w1 + v[0][p + 2] * w2
                    + v[1][p] * w3 + v[1][p + 1] * w4 + v[1][p + 2] * w5
                    + v[2][p] * w6 + v[2][p + 1] * w7 + v[2][p + 2] * w8;
            (&o.x)[p] = gelu_f(s * sc + sh);
        }
        *(float4*)(convx + ((size_t)b * Cc + ch0 + ch) * Ntok
                   + (size_t)gy * Wim + xq) = o;
    }
}

// ---------------------------------------------------------------------------
// K6 v4: 64-token blocks (grid 256 x B) to cut unified regs 240 -> ~150 and
// allow 3 blocks/CU. Wave tile 32 tok x 96 col: acc[2][6]=48 + accS[2]=8
// AGPR. A staging: thread = (token an, 8-ch quarter akh). + T14 prefetch.
// ---------------------------------------------------------------------------
__global__ __launch_bounds__(256, 3) void k_final_mfma(const float* __restrict__ vbuf,
                                                       const float* __restrict__ convx,
                                                       const __bf16* __restrict__ Pt,
                                                       const float* __restrict__ si_w1,
                                                       const float* __restrict__ si_b1,
                                                       const float* __restrict__ bn3_g,
                                                       const float* __restrict__ bn3_b,
                                                       const float* __restrict__ bn3_m,
                                                       const float* __restrict__ bn3_v,
                                                       const float* __restrict__ si_w2,
                                                       const float* __restrict__ si_b2,
                                                       const float* __restrict__ proj_b,
                                                       float* __restrict__ out)
{
    __shared__ __align__(16) __bf16 Ah[64 * 40];
    __shared__ __align__(16) __bf16 Al[64 * 40];
    __shared__ __align__(16) __bf16 Bh[192 * 40];
    __shared__ __align__(16) __bf16 Bl[192 * 40];
    __shared__ float smbuf[64][17];
    __shared__ float ssp_s[64];

    const int t = threadIdx.x;
    const int lane = t & 63, wave = t >> 6;
    const int n0 = blockIdx.x * 64;
    const int b = blockIdx.y;
    const int row_base = (wave & 1) * 32;
    const int col_base = (wave >> 1) * 96;
    const int m16 = lane & 15, q = lane >> 4;

    const int an = t & 63;             // A-staging: token within block
    const int akh = t >> 6;            // A-staging: 8-ch quarter (0..3)
    const __bf16* ptb = Pt + (size_t)b * (2 * 73728);

    f32x4 acc[2][6];
#pragma unroll
    for (int rt = 0; rt < 2; ++rt)
#pragma unroll
        for (int ct = 0; ct < 6; ++ct)
#pragma unroll
            for (int j = 0; j < 4; ++j) acc[rt][ct][j] = 0.f;
    f32x4 accS[2];
#pragma unroll
    for (int rt = 0; rt < 2; ++rt)
#pragma unroll
        for (int j = 0; j < 4; ++j) accS[rt][j] = 0.f;

    float xv[8];
    auto loadA = [&](int ph, int ki2) {
        const int ch0 = ki2 * 32 + akh * 8;
        const float* src = (ph == 0)
            ? convx + ((size_t)b * Cc + ch0) * Ntok + n0 + an
            : vbuf + ((size_t)b * Cc + ch0) * Ntok + n0 + an;
#pragma unroll
        for (int jj = 0; jj < 8; ++jj)
            xv[jj] = src[(size_t)jj * Ntok];
    };
    loadA(0, 0);   // preload phase0, ki0

    for (int phase = 0; phase < 2; ++phase) {
        if (phase == 1) {
#pragma unroll
            for (int rt = 0; rt < 2; ++rt) {
                int row = row_base + rt * 16 + q * 4;
#pragma unroll
                for (int j = 0; j < 4; ++j)
                    smbuf[row + j][m16] = accS[rt][j];
            }
            __syncthreads();
            if (t < 64) {
                float sp = si_b2[0];
#pragma unroll
                for (int o = 0; o < 12; ++o) {
                    float z = smbuf[t][o] + si_b1[o];
                    float sc = bn3_g[o] / sqrtf(bn3_v[o] + EPSBN);
                    z = z * sc + (bn3_b[o] - bn3_m[o] * sc);
                    sp = fmaf(si_w2[o], gelu_f(z), sp);
                }
                ssp_s[t] = sigmoid_f(sp);
            }
            __syncthreads();
        }
        for (int ki = 0; ki < 6; ++ki) {
            const int kc = (phase == 0) ? (ki + 6) : ki;
            // ---- stage A from prefetched regs (apply gate scale here) ----
            {
                const float scale = (phase == 0) ? 1.f : ssp_s[an];
                float sv[8];
#pragma unroll
                for (int jj = 0; jj < 8; ++jj) sv[jj] = xv[jj] * scale;
                bf16x8 vh0, vl0;
                split8(sv, vh0, vl0);
                const int o = an * 40 + akh * 8;
                *(bf16x8*)&Ah[o] = vh0;
                *(bf16x8*)&Al[o] = vl0;
            }
            // ---- stage B from pre-split planes ----
#pragma unroll
            for (int i = 0; i < 3; ++i) {
                int f = i * 256 + t;
                int col = f >> 2, k8 = (f & 3) << 3;
                const __bf16* sp = ptb + (size_t)col * 384 + kc * 32 + k8;
                bf16x8 vh = *(const bf16x8*)sp;
                bf16x8 vl = *(const bf16x8*)(sp + 73728);
                *(bf16x8*)&Bh[col * 40 + k8] = vh;
                *(bf16x8*)&Bl[col * 40 + k8] = vl;
            }
            // ---- prefetch next A (flies across barriers) ----
            if (ki < 5) loadA(phase, ki + 1);
            else if (phase == 0) loadA(1, 0);
            __syncthreads();

            bf16x8 fah[2], fal[2], fbh[6], fbl[6];
#pragma unroll
            for (int rt = 0; rt < 2; ++rt) {
                int o = (row_base + rt * 16 + m16) * 40 + q * 8;
                fah[rt] = *(const bf16x8*)&Ah[o];
                fal[rt] = *(const bf16x8*)&Al[o];
            }
#pragma unroll
            for (int ct = 0; ct < 6; ++ct) {
                int o = (col_base + ct * 16 + m16) * 40 + q * 8;
                fbh[ct] = *(const bf16x8*)&Bh[o];
            }
#pragma unroll
            for (int rt = 0; rt < 2; ++rt)
#pragma unroll
                for (int ct = 0; ct < 6; ++ct) {
                    acc[rt][ct] = __builtin_amdgcn_mfma_f32_16x16x32_bf16(
                        fah[rt], fbh[ct], acc[rt][ct], 0, 0, 0);
                    acc[rt][ct] = __builtin_amdgcn_mfma_f32_16x16x32_bf16(
                        fal[rt], fbh[ct], acc[rt][ct], 0, 0, 0);
                }
#pragma unroll
            for (int ct = 0; ct < 6; ++ct) {
                int o = (col_base + ct * 16 + m16) * 40 + q * 8;
                fbl[ct] = *(const bf16x8*)&Bl[o];
            }
#pragma unroll
            for (int rt = 0; rt < 2; ++rt)
#pragma unroll
                for (int ct = 0; ct < 6; ++ct)
                    acc[rt][ct] = __builtin_amdgcn_mfma_f32_16x16x32_bf16(
                        fah[rt], fbl[ct], acc[rt][ct], 0, 0, 0);

            if (phase == 0) {
                bf16x8 w1h, w1l;
                if (m16 < 12) {
                    const float* wp = si_w1 + m16 * 192 + ki * 32 + q * 8;
                    float wv[8];
                    float4 u0 = *(const float4*)wp, u1 = *(const float4*)(wp + 4);
                    wv[0] = u0.x; wv[1] = u0.y; wv[2] = u0.z; wv[3] = u0.w;
                    wv[4] = u1.x; wv[5] = u1.y; wv[6] = u1.z; wv[7] = u1.w;
                    split8(wv, w1h, w1l);
                } else {
#pragma unroll
                    for (int j = 0; j < 8; ++j) { w1h[j] = (__bf16)0.f; w1l[j] = (__bf16)0.f; }
                }
#pragma unroll
                for (int rt = 0; rt < 2; ++rt) {
                    accS[rt] = __builtin_amdgcn_mfma_f32_16x16x32_bf16(
                        fah[rt], w1h, accS[rt], 0, 0, 0);
                    accS[rt] = __builtin_amdgcn_mfma_f32_16x16x32_bf16(
                        fal[rt], w1h, accS[rt], 0, 0, 0);
                    accS[rt] = __builtin_amdgcn_mfma_f32_16x16x32_bf16(
                        fah[rt], w1l, accS[rt], 0, 0, 0);
                }
            }
            __syncthreads();
        }
    }

    // ---- epilogue: out (B,N,C) token-major + proj_b ----
    float* ob = out + ((size_t)b * Ntok + n0) * Cc;
#pragma unroll
    for (int ct = 0; ct < 6; ++ct) {
        const int col = col_base + ct * 16 + m16;
        const float pbv = proj_b[col];
#pragma unroll
        for (int rt = 0; rt < 2; ++rt) {
            const int row = row_base + rt * 16 + q * 4;
#pragma unroll
            for (int j = 0; j < 4; ++j)
                ob[(size_t)(row + j) * Cc + col] = acc[rt][ct][j] + pbv;
        }
    }
}

extern "C" void kernel_launch(void* const* d_in, const int* in_sizes, int n_in,
                              void* d_out, int out_size, void* d_ws, size_t ws_size,
                              hipStream_t stream)
{
    const float* x      = (const float*)d_in[0];
    const float* w_qkv  = (const float*)d_in[3];
    const float* temperature = (const float*)d_in[4];
    const float* dw_w   = (const float*)d_in[5];
    const float* dw_b   = (const float*)d_in[6];
    const float* bn1_g  = (const float*)d_in[7];
    const float* bn1_b  = (const float*)d_in[8];
    const float* bn1_m  = (const float*)d_in[9];
    const float* bn1_v  = (const float*)d_in[10];
    const float* ci_w1  = (const float*)d_in[11];
    const float* ci_b1  = (const float*)d_in[12];
    const float* bn2_g  = (const float*)d_in[13];
    const float* bn2_b  = (const float*)d_in[14];
    const float* bn2_m  = (const float*)d_in[15];
    const float* bn2_v  = (const float*)d_in[16];
    const float* ci_w2  = (const float*)d_in[17];
    const float* ci_b2  = (const float*)d_in[18];
    const float* si_w1  = (const float*)d_in[19];
    const float* si_b1  = (const float*)d_in[20];
    const float* bn3_g  = (const float*)d_in[21];
    const float* bn3_b  = (const float*)d_in[22];
    const float* bn3_m  = (const float*)d_in[23];
    const float* bn3_v  = (const float*)d_in[24];
    const float* si_w2  = (const float*)d_in[25];
    const float* si_b2  = (const float*)d_in[26];
    const float* proj_w = (const float*)d_in[27];
    const float* proj_b = (const float*)d_in[28];

    float* ws = (float*)d_ws;
    const size_t BCN = (size_t)Bb * Cc * Ntok;      // 25,165,824
    float* vbuf  = ws;
    float* convx = ws + BCN;
    __bf16* Pt   = (__bf16*)(ws + 2 * BCN);         // 8*2*73728 bf16 = 589824 f
    float* xpart = ws + 2 * BCN + 589824;           // 256*36864 = 9,437,184
    float* XtX   = xpart + 9437184;                 // 294,912
    float* gram  = XtX + 294912;                    // 36864
    float* ssq_q = gram + 36864;                    // 1536
    float* ssq_k = ssq_q + 1536;                    // 1536
    float* vmean = ssq_k + 1536;                    // 1536 (holds channel SUMS)
    float* attn  = vmean + 1536;                    // 36864
    float* sig_ch = attn + 36864;                   // 1536
    float* out = (float*)d_out;

    __bf16* wt = (__bf16*)(out + BCN - 36864);      // 73728 bf16 in out tail

    hipMemsetAsync(vmean, 0, 1536 * sizeof(float), stream);

    k_wprep<<<dim3(144), 256, 0, stream>>>(w_qkv, wt);
    k_xtx<<<dim3(32, Bb), 512, 0, stream>>>(x, xpart);
    k_xred<<<dim3(144, Bb), 256, 0, stream>>>(xpart, XtX);
    k_gram2<<<dim3(Bb, NHEADS), 256, 0, stream>>>(XtX, w_qkv, gram, ssq_q, ssq_k);
    k_qkv_mfma<<<dim3(Ntok / 64, Bb), 256, 0, stream>>>(x, wt, vbuf, vmean);
    k_attn<<<dim3(Bb), 256, 0, stream>>>(gram, ssq_q, ssq_k, temperature, vmean,
                                         ci_w1, ci_b1, bn2_g, bn2_b, bn2_m, bn2_v,
                                         ci_w2, ci_b2, attn, sig_ch);
    k_pprep<<<dim3(Bb, 9), 192, 0, stream>>>(attn, sig_ch, proj_w, Pt);
    k_conv<<<dim3(Him / 8, Cc / 8, Bb), 256, 0, stream>>>(
        vbuf, dw_w, dw_b, bn1_g, bn1_b, bn1_m, bn1_v, convx);
    k_final_mfma<<<dim3(Ntok / 64, Bb), 256, 0, stream>>>(
        vbuf, convx, Pt, si_w1, si_b1, bn3_g, bn3_b, bn3_m, bn3_v,
        si_w2, si_b2, proj_b, out);
}